// Round 4
// baseline (534.147 us; speedup 1.0000x reference)
//
#include <hip/hip_runtime.h>
#include <hip/hip_bf16.h>

// GCNBlock: 6-dispatch pipeline.
// h = (x@W) stored bf16 UNSCALED ; gather-aggregate applies dinv[src] per edge ;
// graph-LayerNorm ; PReLU.  N=50000, E=800000, F=256
//
// R4 changes (dispatch-count 9 -> 6, no single-workgroup stages):
//  - CSR ptr build in ONE kernel: block-local scan + atomicAdd(gbase) for the
//    block base (buckets in arbitrary block order -- legal, aggregate only
//    needs start+len).
//  - rank[] eliminated: fill claims slots by atomically bumping csr_ptr[dst];
//    after fill csr_ptr[row]==bucket END, aggregate uses end - deg_cnt[row].
//  - finalize_stats eliminated: aggregate blocks do 2x f64 atomicAdd into
//    gsum[2]; norm_prelu derives mu/inv inline.

#define F 256
#define EPSV 1e-5f

typedef __attribute__((ext_vector_type(8))) short short8;
typedef __attribute__((ext_vector_type(4))) float f32x4;

__device__ __forceinline__ unsigned short f2bf(float f) {
  union { float f; unsigned u; } v; v.f = f;
  unsigned r = v.u + 0x7fffu + ((v.u >> 16) & 1u);  // RNE
  return (unsigned short)(r >> 16);
}

__device__ __forceinline__ float bf2f(unsigned short u) {
  union { unsigned u; float f; } v; v.u = ((unsigned)u) << 16; return v.f;
}

// ---- init: zero deg_cnt/gbase/gsum (blocks < NB) ; prep Wb (blocks >= NB) --

__global__ void init_prep(int* __restrict__ deg_cnt, int N, int NB,
                          const float* __restrict__ W, unsigned short* __restrict__ Wb,
                          int* __restrict__ gbase, double* __restrict__ gsum) {
  if ((int)blockIdx.x < NB) {
    int i = blockIdx.x * 256 + threadIdx.x;
    if (i < N) deg_cnt[i] = 0;
    if (blockIdx.x == 0 && threadIdx.x == 0) {
      *gbase = 0;
      gsum[0] = 0.0;
      gsum[1] = 0.0;
    }
    return;
  }
  int gid = (blockIdx.x - NB) * 256 + threadIdx.x;  // 65536 total
  int j = gid & 7;
  int lane = (gid >> 3) & 63;
  int kc = (gid >> 9) & 7;
  int tt = gid >> 12;
  int k = kc * 32 + (lane >> 4) * 8 + j;
  int n = tt * 16 + (lane & 15);
  Wb[gid] = f2bf(W[k * 256 + n]);
}

// ---- count (blocks < eb) ; gemm 64-row tiles (blocks >= eb) ----------------
// GEMM writes h bf16 UNSCALED (dinv applied at gather time in aggregate).

__global__ void count_gemm(const int* __restrict__ dst, int* __restrict__ deg_cnt,
                           int E, int eb,
                           const float* __restrict__ x, const unsigned short* __restrict__ Wb,
                           ushort4* __restrict__ hb, int N) {
  // A-tile staging AND epilogue repack share this buffer.
  // +8 pad: row stride 528B -> rows offset by 4 banks -> conflict-free b128 reads.
  __shared__ unsigned short A[64][264];  // 33792 B -> 4 blocks/CU

  if ((int)blockIdx.x < eb) {
    int e = blockIdx.x * 256 + threadIdx.x;
    if (e < E) atomicAdd(&deg_cnt[dst[e]], 1);
    return;
  }

  int bid = blockIdx.x - eb;
  int m0 = bid * 64;
  int t = threadIdx.x;
  int lane = t & 63;
  int wave = t >> 6;
  int q = lane >> 4;

  // ---- stage A: 64 rows x 256 cols, fp32 -> bf16, fully coalesced ----------
#pragma unroll
  for (int j = 0; j < 16; ++j) {
    int idx = j * 256 + t;      // 0..4095 float4s
    int row = idx >> 6;         // 0..63
    int c4 = idx & 63;          // float4 within row
    int gr = m0 + row;
    int grc = gr < N ? gr : N - 1;
    f32x4 v = __builtin_nontemporal_load((const f32x4*)(x + (size_t)grc * F + c4 * 4));
    ushort4 u;
    u.x = f2bf(v[0]); u.y = f2bf(v[1]); u.z = f2bf(v[2]); u.w = f2bf(v[3]);
    *(ushort4*)&A[row][c4 * 4] = u;
  }
  __syncthreads();

  // ---- compute: each wave owns 64 rows x 64 cols (4 m-tiles x 4 n-tiles) ---
  f32x4 acc[4][4];
#pragma unroll
  for (int m = 0; m < 4; ++m)
#pragma unroll
    for (int tt = 0; tt < 4; ++tt)
      acc[m][tt] = (f32x4){0.f, 0.f, 0.f, 0.f};

  int arow = lane & 15;
  for (int kc = 0; kc < 8; ++kc) {
    short8 a[4];
#pragma unroll
    for (int m = 0; m < 4; ++m)
      a[m] = *(const short8*)&A[m * 16 + arow][kc * 32 + q * 8];
#pragma unroll
    for (int tt = 0; tt < 4; ++tt) {
      const short8 b = *(const short8*)(Wb + (((wave * 4 + tt) * 8 + kc) * 64 + lane) * 8);
#pragma unroll
      for (int m = 0; m < 4; ++m)
        acc[m][tt] = __builtin_amdgcn_mfma_f32_16x16x32_bf16(a[m], b, acc[m][tt], 0, 0, 0);
    }
  }

  __syncthreads();  // all waves done reading A before repack overwrites it

  // ---- epilogue: bf16, repack via LDS, coalesced store (NO dinv scaling) ---
  int ccol = lane & 15;
#pragma unroll
  for (int m = 0; m < 4; ++m) {
#pragma unroll
    for (int rr = 0; rr < 4; ++rr) {
      int lrow = m * 16 + q * 4 + rr;
#pragma unroll
      for (int tt = 0; tt < 4; ++tt)
        A[lrow][(wave * 4 + tt) * 16 + ccol] = f2bf(acc[m][tt][rr]);
    }
  }
  __syncthreads();
#pragma unroll
  for (int j = 0; j < 16; ++j) {
    int idx = j * 256 + t;
    int row = idx >> 6;
    int c4 = idx & 63;
    int grow = m0 + row;
    if (grow < N) hb[(size_t)grow * 64 + c4] = *(const ushort4*)&A[row][c4 * 4];
  }
}

// ---- CSR ptr build: one kernel, block scan + atomic base -------------------
// Buckets land in arbitrary block order (legal: aggregate uses start+len).

__global__ void build_ptr(const int* __restrict__ deg_cnt, float* __restrict__ dinv,
                          int* __restrict__ csr_ptr, int* __restrict__ gbase, int N) {
  __shared__ int s[256];
  __shared__ int base;
  int t = threadIdx.x;
  int i = blockIdx.x * 256 + t;
  int d = (i < N) ? deg_cnt[i] : 0;
  if (i < N) dinv[i] = rsqrtf((float)(d + 1));  // +1 self loop
  s[t] = d;
  __syncthreads();
  for (int off = 1; off < 256; off <<= 1) {
    int x = (t >= off) ? s[t - off] : 0;
    __syncthreads();
    s[t] += x;
    __syncthreads();
  }
  if (t == 255) base = atomicAdd(gbase, s[255]);
  __syncthreads();
  if (i < N) csr_ptr[i] = base + s[t] - d;  // exclusive (bucket START)
}

// ---- fill: claim slot by bumping csr_ptr[dst] ------------------------------
// After this kernel csr_ptr[row] == bucket END.

__global__ void fill(const int* __restrict__ src, const int* __restrict__ dst,
                     int* __restrict__ csr_ptr, int* __restrict__ csr_src, int E) {
  int e = blockIdx.x * 256 + threadIdx.x;
  if (e < E) {
    int pos = atomicAdd(&csr_ptr[dst[e]], 1);
    csr_src[pos] = src[e];
  }
}

// ---- Aggregation: one row per wave, 16-way unrolled bf16 gather ------------
// hb is UNSCALED; per-edge weight w[j] = dinv[src_j] (0 for pad lanes).
// csr_ptr[row] is bucket END; start = end - deg_cnt[row].
// Stats: 2x f64 atomicAdd per block into gsum[2].

__global__ void aggregate(const ushort4* __restrict__ hb, const int* __restrict__ csr_ptr,
                          const int* __restrict__ deg_cnt, const int* __restrict__ csr_src,
                          const float* __restrict__ dinv, const float* __restrict__ conv_bias,
                          float* __restrict__ out, double* __restrict__ gsum, int N) {
  int wave = threadIdx.x >> 6;
  int lane = threadIdx.x & 63;
  int row = blockIdx.x * 4 + wave;
  float s1 = 0.f, s2 = 0.f;

  if (row < N) {
    float di = dinv[row];
    int b1 = csr_ptr[row];
    int b0 = b1 - deg_cnt[row];
    ushort4 self = hb[(size_t)row * 64 + lane];
    f32x4 acc;
    acc[0] = bf2f(self.x) * di; acc[1] = bf2f(self.y) * di;
    acc[2] = bf2f(self.z) * di; acc[3] = bf2f(self.w) * di;

    for (int e = b0; e < b1; e += 16) {
      int idx[16];
#pragma unroll
      for (int j = 0; j < 16; ++j) {
        int ee = e + j;
        idx[j] = csr_src[ee < b1 ? ee : b1 - 1];
      }
      ushort4 v[16];
#pragma unroll
      for (int j = 0; j < 16; ++j) v[j] = hb[(size_t)idx[j] * 64 + lane];
      float w[16];
#pragma unroll
      for (int j = 0; j < 16; ++j) w[j] = dinv[idx[j]];
#pragma unroll
      for (int j = 0; j < 16; ++j) {
        float m = (e + j < b1) ? w[j] : 0.f;
        acc[0] = fmaf(bf2f(v[j].x), m, acc[0]);
        acc[1] = fmaf(bf2f(v[j].y), m, acc[1]);
        acc[2] = fmaf(bf2f(v[j].z), m, acc[2]);
        acc[3] = fmaf(bf2f(v[j].w), m, acc[3]);
      }
    }

    const f32x4 b = *(const f32x4*)(conv_bias + lane * 4);
    acc[0] = fmaf(acc[0], di, b[0]);
    acc[1] = fmaf(acc[1], di, b[1]);
    acc[2] = fmaf(acc[2], di, b[2]);
    acc[3] = fmaf(acc[3], di, b[3]);
    __builtin_nontemporal_store(acc, (f32x4*)(out + ((size_t)row * 64 + lane) * 4));
    s1 = acc[0] + acc[1] + acc[2] + acc[3];
    s2 = acc[0] * acc[0] + acc[1] * acc[1] + acc[2] * acc[2] + acc[3] * acc[3];
  }

  __shared__ float r1[256];
  __shared__ float r2[256];
  int t = threadIdx.x;
  r1[t] = s1;
  r2[t] = s2;
  __syncthreads();
  for (int off = 128; off > 0; off >>= 1) {
    if (t < off) { r1[t] += r1[t + off]; r2[t] += r2[t + off]; }
    __syncthreads();
  }
  if (t == 0) {
    atomicAdd(&gsum[0], (double)r1[0]);
    atomicAdd(&gsum[1], (double)r2[0]);
  }
}

// ---- LayerNorm(graph) + PReLU; mu/inv derived inline from gsum -------------

__global__ void norm_prelu(float* __restrict__ out, const double* __restrict__ gsum,
                           const float* __restrict__ lw, const float* __restrict__ lb,
                           const float* __restrict__ pa, int n4, double cnt) {
  int i = blockIdx.x * blockDim.x + threadIdx.x;
  if (i >= n4) return;
  double g1 = gsum[0];
  double g2 = gsum[1];
  double mud = g1 / cnt;
  double var = g2 / cnt - mud * mud;
  if (var < 0) var = 0;
  float mu = (float)mud;
  float inv = (float)(1.0 / (sqrt(var) + (double)EPSV));
  float a = pa[0];
  int c4 = (i & 63) * 4;
  const f32x4 w = *(const f32x4*)(lw + c4);
  const f32x4 b = *(const f32x4*)(lb + c4);
  f32x4 v = __builtin_nontemporal_load((const f32x4*)(out + (size_t)i * 4));
  f32x4 y;
#pragma unroll
  for (int j = 0; j < 4; ++j) {
    float yv = (v[j] - mu) * inv * w[j] + b[j];
    y[j] = yv >= 0.f ? yv : a * yv;
  }
  __builtin_nontemporal_store(y, (f32x4*)(out + (size_t)i * 4));
}

// ---- launch ---------------------------------------------------------------

extern "C" void kernel_launch(void* const* d_in, const int* in_sizes, int n_in,
                              void* d_out, int out_size, void* d_ws, size_t ws_size,
                              hipStream_t stream) {
  const float* x = (const float*)d_in[0];
  const int* eidx = (const int*)d_in[1];
  const float* W = (const float*)d_in[3];
  const float* conv_bias = (const float*)d_in[4];
  const float* ln_w = (const float*)d_in[5];
  const float* ln_b = (const float*)d_in[6];
  const float* prelu_a = (const float*)d_in[7];
  float* out = (float*)d_out;

  int N = in_sizes[0] / F;
  int E = in_sizes[1] / 2;
  const int* src = eidx;
  const int* dst = eidx + E;

  int nAggBlocks = (N + 3) / 4;
  int eb = (E + 255) / 256;
  int gemmb = (N + 63) / 64;
  int NB = (N + 255) / 256;

  char* p = (char*)d_ws;
  auto carve = [&](size_t bytes) { char* r = p; p += (bytes + 255) & ~(size_t)255; return r; };
  ushort4* hb    = (ushort4*)carve((size_t)N * 64 * sizeof(ushort4));  // bf16 h (unscaled)
  unsigned short* Wb = (unsigned short*)carve((size_t)F * F * sizeof(short));
  int* deg_cnt   = (int*)carve((size_t)N * sizeof(int));
  float* dinv    = (float*)carve((size_t)N * sizeof(float));
  int* csr_ptr   = (int*)carve((size_t)N * sizeof(int));
  int* csr_src   = (int*)carve((size_t)E * sizeof(int));
  int* gbase     = (int*)carve(sizeof(int));
  double* gsum   = (double*)carve(2 * sizeof(double));

  init_prep<<<NB + 256, 256, 0, stream>>>(deg_cnt, N, NB, W, Wb, gbase, gsum);
  count_gemm<<<eb + gemmb, 256, 0, stream>>>(dst, deg_cnt, E, eb, x, Wb, hb, N);
  build_ptr<<<NB, 256, 0, stream>>>(deg_cnt, dinv, csr_ptr, gbase, N);
  fill<<<eb, 256, 0, stream>>>(src, dst, csr_ptr, csr_src, E);
  aggregate<<<nAggBlocks, 256, 0, stream>>>(hb, csr_ptr, deg_cnt, csr_src, dinv,
                                            conv_bias, out, gsum, N);
  int n4 = N * (F / 4);
  norm_prelu<<<(n4 + 255) / 256, 256, 0, stream>>>(out, gsum, ln_w, ln_b, prelu_a,
                                                   n4, (double)N * (double)F);
}

// Round 5
// 304.771 us; speedup vs baseline: 1.7526x; 1.7526x over previous
//
#include <hip/hip_runtime.h>
#include <hip/hip_bf16.h>

// GCNBlock: 6-dispatch pipeline.
// h = (x@W) stored bf16 UNSCALED ; gather-aggregate applies dinv[src] per edge ;
// graph-LayerNorm ; PReLU.  N=50000, E=800000, F=256
//
// R5 changes (fix R4's 4.4x aggregate regression):
//  - Stats via per-block partials[] store (atomic-free) -- R4's f64 atomicAdd
//    to a single address compiled to a CAS loop; 25K contending CAS across
//    8 XCDs stalled block retirement (aggregate 71.5 -> 316us). REVERTED.
//  - partials reduction folded into norm_prelu (each of 256 blocks redundantly
//    tree-reduces 12.5K double2 = L3-broadcast ~51MB, ~5us) -- keeps 6
//    dispatches, no single-workgroup stage, no FP atomics.
//  - Kept from R4: one-kernel CSR build (block scan + atomic base), rank[]
//    eliminated (fill bumps csr_ptr[dst]; aggregate uses end - deg).

#define F 256
#define EPSV 1e-5f

typedef __attribute__((ext_vector_type(8))) short short8;
typedef __attribute__((ext_vector_type(4))) float f32x4;

__device__ __forceinline__ unsigned short f2bf(float f) {
  union { float f; unsigned u; } v; v.f = f;
  unsigned r = v.u + 0x7fffu + ((v.u >> 16) & 1u);  // RNE
  return (unsigned short)(r >> 16);
}

__device__ __forceinline__ float bf2f(unsigned short u) {
  union { unsigned u; float f; } v; v.u = ((unsigned)u) << 16; return v.f;
}

// ---- init: zero deg_cnt/gbase (blocks < NB) ; prep Wb (blocks >= NB) -------

__global__ void init_prep(int* __restrict__ deg_cnt, int N, int NB,
                          const float* __restrict__ W, unsigned short* __restrict__ Wb,
                          int* __restrict__ gbase) {
  if ((int)blockIdx.x < NB) {
    int i = blockIdx.x * 256 + threadIdx.x;
    if (i < N) deg_cnt[i] = 0;
    if (blockIdx.x == 0 && threadIdx.x == 0) *gbase = 0;
    return;
  }
  int gid = (blockIdx.x - NB) * 256 + threadIdx.x;  // 65536 total
  int j = gid & 7;
  int lane = (gid >> 3) & 63;
  int kc = (gid >> 9) & 7;
  int tt = gid >> 12;
  int k = kc * 32 + (lane >> 4) * 8 + j;
  int n = tt * 16 + (lane & 15);
  Wb[gid] = f2bf(W[k * 256 + n]);
}

// ---- count (blocks < eb) ; gemm 64-row tiles (blocks >= eb) ----------------
// GEMM writes h bf16 UNSCALED (dinv applied at gather time in aggregate).

__global__ void count_gemm(const int* __restrict__ dst, int* __restrict__ deg_cnt,
                           int E, int eb,
                           const float* __restrict__ x, const unsigned short* __restrict__ Wb,
                           ushort4* __restrict__ hb, int N) {
  // A-tile staging AND epilogue repack share this buffer.
  // +8 pad: row stride 528B -> rows offset by 4 banks -> conflict-free b128 reads.
  __shared__ unsigned short A[64][264];  // 33792 B -> 4 blocks/CU

  if ((int)blockIdx.x < eb) {
    int e = blockIdx.x * 256 + threadIdx.x;
    if (e < E) atomicAdd(&deg_cnt[dst[e]], 1);
    return;
  }

  int bid = blockIdx.x - eb;
  int m0 = bid * 64;
  int t = threadIdx.x;
  int lane = t & 63;
  int wave = t >> 6;
  int q = lane >> 4;

  // ---- stage A: 64 rows x 256 cols, fp32 -> bf16, fully coalesced ----------
#pragma unroll
  for (int j = 0; j < 16; ++j) {
    int idx = j * 256 + t;      // 0..4095 float4s
    int row = idx >> 6;         // 0..63
    int c4 = idx & 63;          // float4 within row
    int gr = m0 + row;
    int grc = gr < N ? gr : N - 1;
    f32x4 v = __builtin_nontemporal_load((const f32x4*)(x + (size_t)grc * F + c4 * 4));
    ushort4 u;
    u.x = f2bf(v[0]); u.y = f2bf(v[1]); u.z = f2bf(v[2]); u.w = f2bf(v[3]);
    *(ushort4*)&A[row][c4 * 4] = u;
  }
  __syncthreads();

  // ---- compute: each wave owns 64 rows x 64 cols (4 m-tiles x 4 n-tiles) ---
  f32x4 acc[4][4];
#pragma unroll
  for (int m = 0; m < 4; ++m)
#pragma unroll
    for (int tt = 0; tt < 4; ++tt)
      acc[m][tt] = (f32x4){0.f, 0.f, 0.f, 0.f};

  int arow = lane & 15;
  for (int kc = 0; kc < 8; ++kc) {
    short8 a[4];
#pragma unroll
    for (int m = 0; m < 4; ++m)
      a[m] = *(const short8*)&A[m * 16 + arow][kc * 32 + q * 8];
#pragma unroll
    for (int tt = 0; tt < 4; ++tt) {
      const short8 b = *(const short8*)(Wb + (((wave * 4 + tt) * 8 + kc) * 64 + lane) * 8);
#pragma unroll
      for (int m = 0; m < 4; ++m)
        acc[m][tt] = __builtin_amdgcn_mfma_f32_16x16x32_bf16(a[m], b, acc[m][tt], 0, 0, 0);
    }
  }

  __syncthreads();  // all waves done reading A before repack overwrites it

  // ---- epilogue: bf16, repack via LDS, coalesced store (NO dinv scaling) ---
  int ccol = lane & 15;
#pragma unroll
  for (int m = 0; m < 4; ++m) {
#pragma unroll
    for (int rr = 0; rr < 4; ++rr) {
      int lrow = m * 16 + q * 4 + rr;
#pragma unroll
      for (int tt = 0; tt < 4; ++tt)
        A[lrow][(wave * 4 + tt) * 16 + ccol] = f2bf(acc[m][tt][rr]);
    }
  }
  __syncthreads();
#pragma unroll
  for (int j = 0; j < 16; ++j) {
    int idx = j * 256 + t;
    int row = idx >> 6;
    int c4 = idx & 63;
    int grow = m0 + row;
    if (grow < N) hb[(size_t)grow * 64 + c4] = *(const ushort4*)&A[row][c4 * 4];
  }
}

// ---- CSR ptr build: one kernel, block scan + atomic base -------------------
// Buckets land in arbitrary block order (legal: aggregate uses start+len).

__global__ void build_ptr(const int* __restrict__ deg_cnt, float* __restrict__ dinv,
                          int* __restrict__ csr_ptr, int* __restrict__ gbase, int N) {
  __shared__ int s[256];
  __shared__ int base;
  int t = threadIdx.x;
  int i = blockIdx.x * 256 + t;
  int d = (i < N) ? deg_cnt[i] : 0;
  if (i < N) dinv[i] = rsqrtf((float)(d + 1));  // +1 self loop
  s[t] = d;
  __syncthreads();
  for (int off = 1; off < 256; off <<= 1) {
    int x = (t >= off) ? s[t - off] : 0;
    __syncthreads();
    s[t] += x;
    __syncthreads();
  }
  if (t == 255) base = atomicAdd(gbase, s[255]);
  __syncthreads();
  if (i < N) csr_ptr[i] = base + s[t] - d;  // exclusive (bucket START)
}

// ---- fill: claim slot by bumping csr_ptr[dst] ------------------------------
// After this kernel csr_ptr[row] == bucket END.

__global__ void fill(const int* __restrict__ src, const int* __restrict__ dst,
                     int* __restrict__ csr_ptr, int* __restrict__ csr_src, int E) {
  int e = blockIdx.x * 256 + threadIdx.x;
  if (e < E) {
    int pos = atomicAdd(&csr_ptr[dst[e]], 1);
    csr_src[pos] = src[e];
  }
}

// ---- Aggregation: one row per wave, 16-way unrolled bf16 gather ------------
// hb is UNSCALED; per-edge weight w[j] = dinv[src_j] (0 for pad lanes).
// csr_ptr[row] is bucket END; start = end - deg_cnt[row].
// Stats: per-block double2 partials store (NO atomics -- see R5 note).

__global__ void aggregate(const ushort4* __restrict__ hb, const int* __restrict__ csr_ptr,
                          const int* __restrict__ deg_cnt, const int* __restrict__ csr_src,
                          const float* __restrict__ dinv, const float* __restrict__ conv_bias,
                          float* __restrict__ out, double2* __restrict__ partials, int N) {
  int wave = threadIdx.x >> 6;
  int lane = threadIdx.x & 63;
  int row = blockIdx.x * 4 + wave;
  float s1 = 0.f, s2 = 0.f;

  if (row < N) {
    float di = dinv[row];
    int b1 = csr_ptr[row];
    int b0 = b1 - deg_cnt[row];
    ushort4 self = hb[(size_t)row * 64 + lane];
    f32x4 acc;
    acc[0] = bf2f(self.x) * di; acc[1] = bf2f(self.y) * di;
    acc[2] = bf2f(self.z) * di; acc[3] = bf2f(self.w) * di;

    for (int e = b0; e < b1; e += 16) {
      int idx[16];
#pragma unroll
      for (int j = 0; j < 16; ++j) {
        int ee = e + j;
        idx[j] = csr_src[ee < b1 ? ee : b1 - 1];
      }
      ushort4 v[16];
#pragma unroll
      for (int j = 0; j < 16; ++j) v[j] = hb[(size_t)idx[j] * 64 + lane];
      float w[16];
#pragma unroll
      for (int j = 0; j < 16; ++j) w[j] = dinv[idx[j]];
#pragma unroll
      for (int j = 0; j < 16; ++j) {
        float m = (e + j < b1) ? w[j] : 0.f;
        acc[0] = fmaf(bf2f(v[j].x), m, acc[0]);
        acc[1] = fmaf(bf2f(v[j].y), m, acc[1]);
        acc[2] = fmaf(bf2f(v[j].z), m, acc[2]);
        acc[3] = fmaf(bf2f(v[j].w), m, acc[3]);
      }
    }

    const f32x4 b = *(const f32x4*)(conv_bias + lane * 4);
    acc[0] = fmaf(acc[0], di, b[0]);
    acc[1] = fmaf(acc[1], di, b[1]);
    acc[2] = fmaf(acc[2], di, b[2]);
    acc[3] = fmaf(acc[3], di, b[3]);
    __builtin_nontemporal_store(acc, (f32x4*)(out + ((size_t)row * 64 + lane) * 4));
    s1 = acc[0] + acc[1] + acc[2] + acc[3];
    s2 = acc[0] * acc[0] + acc[1] * acc[1] + acc[2] * acc[2] + acc[3] * acc[3];
  }

  __shared__ float r1[256];
  __shared__ float r2[256];
  int t = threadIdx.x;
  r1[t] = s1;
  r2[t] = s2;
  __syncthreads();
  for (int off = 128; off > 0; off >>= 1) {
    if (t < off) { r1[t] += r1[t + off]; r2[t] += r2[t + off]; }
    __syncthreads();
  }
  if (t == 0) {
    double2 pp;
    pp.x = (double)r1[0];
    pp.y = (double)r2[0];
    partials[blockIdx.x] = pp;
  }
}

// ---- LayerNorm(graph) + PReLU; each block redundantly reduces partials -----
// (L3-broadcast reads, ~51MB total across 256 blocks; no FP atomics)

__global__ void norm_prelu(float* __restrict__ out, const double2* __restrict__ partials,
                           int nb, const float* __restrict__ lw, const float* __restrict__ lb,
                           const float* __restrict__ pa, int n4, double cnt) {
  __shared__ double q1[1024];
  __shared__ double q2[1024];
  __shared__ float sstats[2];
  int t = threadIdx.x;
  double a1 = 0.0, a2 = 0.0;
  for (int i = t; i < nb; i += 1024) {
    double2 pp = partials[i];
    a1 += pp.x;
    a2 += pp.y;
  }
  q1[t] = a1;
  q2[t] = a2;
  __syncthreads();
  for (int off = 512; off > 0; off >>= 1) {
    if (t < off) { q1[t] += q1[t + off]; q2[t] += q2[t + off]; }
    __syncthreads();
  }
  if (t == 0) {
    double mu = q1[0] / cnt;
    double var = q2[0] / cnt - mu * mu;
    if (var < 0) var = 0;
    sstats[0] = (float)mu;
    sstats[1] = (float)(1.0 / (sqrt(var) + (double)EPSV));
  }
  __syncthreads();
  float mu = sstats[0];
  float inv = sstats[1];
  float a = pa[0];
  int stride = gridDim.x * 1024;
  for (int i = blockIdx.x * 1024 + t; i < n4; i += stride) {
    int c4 = (i & 63) * 4;
    const f32x4 w = *(const f32x4*)(lw + c4);
    const f32x4 b = *(const f32x4*)(lb + c4);
    f32x4 v = __builtin_nontemporal_load((const f32x4*)(out + (size_t)i * 4));
    f32x4 y;
#pragma unroll
    for (int j = 0; j < 4; ++j) {
      float yv = (v[j] - mu) * inv * w[j] + b[j];
      y[j] = yv >= 0.f ? yv : a * yv;
    }
    __builtin_nontemporal_store(y, (f32x4*)(out + (size_t)i * 4));
  }
}

// ---- launch ---------------------------------------------------------------

extern "C" void kernel_launch(void* const* d_in, const int* in_sizes, int n_in,
                              void* d_out, int out_size, void* d_ws, size_t ws_size,
                              hipStream_t stream) {
  const float* x = (const float*)d_in[0];
  const int* eidx = (const int*)d_in[1];
  const float* W = (const float*)d_in[3];
  const float* conv_bias = (const float*)d_in[4];
  const float* ln_w = (const float*)d_in[5];
  const float* ln_b = (const float*)d_in[6];
  const float* prelu_a = (const float*)d_in[7];
  float* out = (float*)d_out;

  int N = in_sizes[0] / F;
  int E = in_sizes[1] / 2;
  const int* src = eidx;
  const int* dst = eidx + E;

  int nAggBlocks = (N + 3) / 4;
  int eb = (E + 255) / 256;
  int gemmb = (N + 63) / 64;
  int NB = (N + 255) / 256;

  char* p = (char*)d_ws;
  auto carve = [&](size_t bytes) { char* r = p; p += (bytes + 255) & ~(size_t)255; return r; };
  ushort4* hb    = (ushort4*)carve((size_t)N * 64 * sizeof(ushort4));  // bf16 h (unscaled)
  unsigned short* Wb = (unsigned short*)carve((size_t)F * F * sizeof(short));
  int* deg_cnt   = (int*)carve((size_t)N * sizeof(int));
  float* dinv    = (float*)carve((size_t)N * sizeof(float));
  int* csr_ptr   = (int*)carve((size_t)N * sizeof(int));
  int* csr_src   = (int*)carve((size_t)E * sizeof(int));
  int* gbase     = (int*)carve(sizeof(int));
  double2* partials = (double2*)carve((size_t)nAggBlocks * sizeof(double2));

  init_prep<<<NB + 256, 256, 0, stream>>>(deg_cnt, N, NB, W, Wb, gbase);
  count_gemm<<<eb + gemmb, 256, 0, stream>>>(dst, deg_cnt, E, eb, x, Wb, hb, N);
  build_ptr<<<NB, 256, 0, stream>>>(deg_cnt, dinv, csr_ptr, gbase, N);
  fill<<<eb, 256, 0, stream>>>(src, dst, csr_ptr, csr_src, E);
  aggregate<<<nAggBlocks, 256, 0, stream>>>(hb, csr_ptr, deg_cnt, csr_src, dinv,
                                            conv_bias, out, partials, N);
  int n4 = N * (F / 4);
  norm_prelu<<<256, 1024, 0, stream>>>(out, partials, nAggBlocks, ln_w, ln_b, prelu_a,
                                       n4, (double)N * (double)F);
}